// Round 1
// baseline (374.835 us; speedup 1.0000x reference)
//
#include <hip/hip_runtime.h>
#include <hip/hip_bf16.h>

typedef __bf16 bf16x8 __attribute__((ext_vector_type(8)));
typedef float f32x4 __attribute__((ext_vector_type(4)));
typedef unsigned short ushort_t;

#define S_LEN 4096
#define D_DIM 512
#define NBATCH 4

static __device__ __forceinline__ ushort_t f2bf(float f) {
    __hip_bfloat16 h = __float2bfloat16(f);
    return __builtin_bit_cast(ushort_t, h);
}

// ---------------- fp32 -> bf16 convert (with optional scale) ----------------
__global__ void cvt_bf16_kernel(const float* __restrict__ src, ushort_t* __restrict__ dst,
                                int n4, float scale) {
    int i = blockIdx.x * blockDim.x + threadIdx.x;
    if (i >= n4) return;
    float4 v = reinterpret_cast<const float4*>(src)[i];
    ushort4 o;
    o.x = f2bf(v.x * scale);
    o.y = f2bf(v.y * scale);
    o.z = f2bf(v.z * scale);
    o.w = f2bf(v.w * scale);
    reinterpret_cast<ushort4*>(dst)[i] = o;
}

// ---------------- generic bf16 GEMM: C[M][N] = A[M][K] * Bt[N][K]^T ----------------
// 128x128 tile, BK=32, 256 threads (4 waves, each 64x64), 16x16x32 MFMA.
__global__ __launch_bounds__(256) void gemm_bt(const ushort_t* __restrict__ A,
                                               const ushort_t* __restrict__ Bt,
                                               ushort_t* __restrict__ C,
                                               int M, int N, int K) {
    __shared__ ushort_t As[128 * 40];  // +8 pad per row (16B) to spread banks
    __shared__ ushort_t Bs[128 * 40];
    int tid = threadIdx.x;
    int w = tid >> 6, lane = tid & 63, c = lane & 15, g = lane >> 4;
    int m0 = blockIdx.x * 128, n0 = blockIdx.y * 128;
    int wm = (w >> 1) * 64, wn = (w & 1) * 64;

    f32x4 acc[4][4];
#pragma unroll
    for (int mi = 0; mi < 4; mi++)
#pragma unroll
        for (int ni = 0; ni < 4; ni++) acc[mi][ni] = (f32x4){0.f, 0.f, 0.f, 0.f};

    for (int k0 = 0; k0 < K; k0 += 32) {
        __syncthreads();
#pragma unroll
        for (int r = 0; r < 2; r++) {
            int cl = r * 256 + tid;          // 0..511 chunk index (16B chunks)
            int row = cl >> 2, cin = cl & 3; // 4 chunks per 32-elem row
            *(bf16x8*)(&As[row * 40 + cin * 8]) =
                *(const bf16x8*)(A + (size_t)(m0 + row) * K + k0 + cin * 8);
            *(bf16x8*)(&Bs[row * 40 + cin * 8]) =
                *(const bf16x8*)(Bt + (size_t)(n0 + row) * K + k0 + cin * 8);
        }
        __syncthreads();

        bf16x8 af[4], bfr[4];
#pragma unroll
        for (int i2 = 0; i2 < 4; i2++)
            af[i2] = *(const bf16x8*)(&As[(wm + i2 * 16 + c) * 40 + g * 8]);
#pragma unroll
        for (int i2 = 0; i2 < 4; i2++)
            bfr[i2] = *(const bf16x8*)(&Bs[(wn + i2 * 16 + c) * 40 + g * 8]);
#pragma unroll
        for (int mi = 0; mi < 4; mi++)
#pragma unroll
            for (int ni = 0; ni < 4; ni++)
                acc[mi][ni] = __builtin_amdgcn_mfma_f32_16x16x32_bf16(af[mi], bfr[ni],
                                                                      acc[mi][ni], 0, 0, 0);
    }

#pragma unroll
    for (int mi = 0; mi < 4; mi++)
#pragma unroll
        for (int ni = 0; ni < 4; ni++)
#pragma unroll
            for (int j = 0; j < 4; j++)
                C[(size_t)(m0 + wm + mi * 16 + g * 4 + j) * N + n0 + wn + ni * 16 + c] =
                    f2bf(acc[mi][ni][j]);
}

// ---------------- flash attention, causal, bf16 inputs, fp32 out ----------------
// One WG per (batch, 64-row q-block). 4 waves x 16 q-rows. KV tile = 64.
// K staged [64][520] (row-pad 16B), V^T staged [512][72], P via per-wave LDS [16][72].
#define KPAD 520
#define VPAD 72
__global__ __launch_bounds__(256, 1) void attn_kernel(const ushort_t* __restrict__ Q,
                                                      const ushort_t* __restrict__ K,
                                                      const ushort_t* __restrict__ Vt,
                                                      float* __restrict__ out) {
    __shared__ ushort_t Ks[64 * KPAD];    // 65 KB
    __shared__ ushort_t Vs[512 * VPAD];   // 72 KB
    __shared__ ushort_t Ps[4 * 16 * VPAD];

    int i = blockIdx.x;
    // XCD swizzle: batch b lives on XCD pair {2b,2b+1} (default round-robin dispatch)
    int b = (i & 7) >> 1;
    int qblk = ((i >> 3) << 1) | (i & 1);
    int tid = threadIdx.x;
    int w = tid >> 6, lane = tid & 63, c = lane & 15, g = lane >> 4;

    const int qbase = qblk * 64;
    const int sbase = b * S_LEN;

    // Q fragments in registers (scale 1/sqrt(512) already folded into W_q)
    bf16x8 qf[16];
    {
        const ushort_t* qrow = Q + (size_t)(sbase + qbase + w * 16 + c) * D_DIM;
#pragma unroll
        for (int kk = 0; kk < 16; kk++)
            qf[kk] = *(const bf16x8*)(qrow + kk * 32 + g * 8);
    }

    f32x4 o[32];
#pragma unroll
    for (int t = 0; t < 32; t++) o[t] = (f32x4){0.f, 0.f, 0.f, 0.f};
    float m_r[4], l_r[4];
#pragma unroll
    for (int j = 0; j < 4; j++) { m_r[j] = -1e30f; l_r[j] = 0.f; }

    const int ntiles = qblk + 1;
    for (int t = 0; t < ntiles; ++t) {
        const int kv0 = t * 64;
        __syncthreads();
        // ---- stage K tile [64][512] and V^T tile [512][64] ----
        {
            const ushort_t* kg = K + (size_t)(sbase + kv0) * D_DIM;
#pragma unroll
            for (int r = 0; r < 16; r++) {
                int cl = r * 256 + tid;           // 4096 chunks
                int row = cl >> 6, cin = cl & 63; // 64 chunks per K row
                *(bf16x8*)(&Ks[row * KPAD + cin * 8]) =
                    *(const bf16x8*)(kg + row * D_DIM + cin * 8);
            }
            const ushort_t* vg = Vt + (size_t)sbase + kv0;
#pragma unroll
            for (int r = 0; r < 16; r++) {
                int cl = r * 256 + tid;
                int row = cl >> 3, cin = cl & 7;  // 8 chunks per Vt row
                *(bf16x8*)(&Vs[row * VPAD + cin * 8]) =
                    *(const bf16x8*)(vg + (size_t)row * (NBATCH * S_LEN) + cin * 8);
            }
        }
        __syncthreads();

        // ---- QK^T : S[16 q][64 kv] per wave ----
        f32x4 s4[4];
#pragma unroll
        for (int nt = 0; nt < 4; nt++) {
            f32x4 acc = (f32x4){0.f, 0.f, 0.f, 0.f};
#pragma unroll
            for (int kk = 0; kk < 16; kk++) {
                bf16x8 kf = *(const bf16x8*)(&Ks[(nt * 16 + c) * KPAD + kk * 32 + g * 8]);
                acc = __builtin_amdgcn_mfma_f32_16x16x32_bf16(qf[kk], kf, acc, 0, 0, 0);
            }
            s4[nt] = acc;
        }

        // ---- causal mask (diagonal tile only) ----
        if (t == ntiles - 1) {
#pragma unroll
            for (int nt = 0; nt < 4; nt++)
#pragma unroll
                for (int j = 0; j < 4; j++) {
                    int qrow = qbase + w * 16 + g * 4 + j;
                    int kvcol = kv0 + nt * 16 + c;
                    if (kvcol > qrow) s4[nt][j] = -1e30f;
                }
        }

        // ---- online softmax (per lane: rows g*4+j, reduce across 16-lane group) ----
        float mx[4];
#pragma unroll
        for (int j = 0; j < 4; j++) {
            float v = fmaxf(fmaxf(s4[0][j], s4[1][j]), fmaxf(s4[2][j], s4[3][j]));
#pragma unroll
            for (int off = 1; off < 16; off <<= 1) v = fmaxf(v, __shfl_xor(v, off, 64));
            mx[j] = v;
        }
        float alpha[4], rs[4];
#pragma unroll
        for (int j = 0; j < 4; j++) {
            float mn = fmaxf(m_r[j], mx[j]);
            alpha[j] = __expf(m_r[j] - mn);
            m_r[j] = mn;
            rs[j] = 0.f;
        }
        ushort_t* pw = &Ps[w * 16 * VPAD];
#pragma unroll
        for (int nt = 0; nt < 4; nt++)
#pragma unroll
            for (int j = 0; j < 4; j++) {
                float p = __expf(s4[nt][j] - m_r[j]);
                rs[j] += p;
                pw[(g * 4 + j) * VPAD + nt * 16 + c] = f2bf(p);
            }
#pragma unroll
        for (int j = 0; j < 4; j++) {
            float v = rs[j];
#pragma unroll
            for (int off = 1; off < 16; off <<= 1) v += __shfl_xor(v, off, 64);
            l_r[j] = l_r[j] * alpha[j] + v;
        }
        // ---- rescale O ----
#pragma unroll
        for (int dt = 0; dt < 32; dt++)
#pragma unroll
            for (int j = 0; j < 4; j++) o[dt][j] *= alpha[j];

        // ---- PV : O += P[16x64] * V[64x512] ----
        bf16x8 pf[2];
#pragma unroll
        for (int kk = 0; kk < 2; kk++)
            pf[kk] = *(const bf16x8*)(&pw[c * VPAD + kk * 32 + g * 8]);
#pragma unroll
        for (int dt = 0; dt < 32; dt++) {
            f32x4 acc = o[dt];
#pragma unroll
            for (int kk = 0; kk < 2; kk++) {
                bf16x8 vf = *(const bf16x8*)(&Vs[(dt * 16 + c) * VPAD + kk * 32 + g * 8]);
                acc = __builtin_amdgcn_mfma_f32_16x16x32_bf16(pf[kk], vf, acc, 0, 0, 0);
            }
            o[dt] = acc;
        }
    }

    // ---- epilogue: normalize and store fp32 ----
    float inv_l[4];
#pragma unroll
    for (int j = 0; j < 4; j++) inv_l[j] = 1.f / l_r[j];
#pragma unroll
    for (int dt = 0; dt < 32; dt++)
#pragma unroll
        for (int j = 0; j < 4; j++)
            out[(size_t)(sbase + qbase + w * 16 + g * 4 + j) * D_DIM + dt * 16 + c] =
                o[dt][j] * inv_l[j];
}

// ---------------- host launch ----------------
extern "C" void kernel_launch(void* const* d_in, const int* in_sizes, int n_in,
                              void* d_out, int out_size, void* d_ws, size_t ws_size,
                              hipStream_t stream) {
    const float* X  = (const float*)d_in[0];
    const float* Wq = (const float*)d_in[1];
    const float* Wk = (const float*)d_in[2];
    const float* Wv = (const float*)d_in[3];
    float* out = (float*)d_out;

    const int M = NBATCH * S_LEN;   // 16384
    const int Kd = D_DIM;           // 512
    const size_t XBF_BYTES = (size_t)M * Kd * 2;       // 16.8 MB
    const size_t W_BYTES   = (size_t)Kd * Kd * 2;      // 0.5 MB

    char* p = (char*)d_ws;
    ushort_t* Xbf = (ushort_t*)p;              p += XBF_BYTES;
    ushort_t* Wqb = (ushort_t*)p;              p += W_BYTES;
    ushort_t* Wkb = (ushort_t*)p;              p += W_BYTES;
    ushort_t* Wvb = (ushort_t*)p;              p += W_BYTES;
    ushort_t* Qb  = (ushort_t*)p;              p += XBF_BYTES;
    ushort_t* Kb  = (ushort_t*)p;              p += XBF_BYTES;
    ushort_t* Vtb = (ushort_t*)p;              p += XBF_BYTES;

    const float qscale = 0.044194173824159216f;  // 1/sqrt(512)

    // converts
    {
        int n4 = (M * Kd) / 4;
        cvt_bf16_kernel<<<(n4 + 255) / 256, 256, 0, stream>>>(X, Xbf, n4, 1.0f);
        int w4 = (Kd * Kd) / 4;
        cvt_bf16_kernel<<<(w4 + 255) / 256, 256, 0, stream>>>(Wq, Wqb, w4, qscale);
        cvt_bf16_kernel<<<(w4 + 255) / 256, 256, 0, stream>>>(Wk, Wkb, w4, 1.0f);
        cvt_bf16_kernel<<<(w4 + 255) / 256, 256, 0, stream>>>(Wv, Wvb, w4, 1.0f);
    }
    // Q = X * Wq^T (scaled), K = X * Wk^T   : C[M=16384][N=512]
    gemm_bt<<<dim3(M / 128, Kd / 128), 256, 0, stream>>>(Xbf, Wqb, Qb, M, Kd, Kd);
    gemm_bt<<<dim3(M / 128, Kd / 128), 256, 0, stream>>>(Xbf, Wkb, Kb, M, Kd, Kd);
    // V^T = Wv * X^T : C[M=512][N=16384]
    gemm_bt<<<dim3(Kd / 128, M / 128), 256, 0, stream>>>(Wvb, Xbf, Vtb, Kd, M, Kd);
    // attention
    attn_kernel<<<256, 256, 0, stream>>>(Qb, Kb, Vtb, out);
}